// Round 2
// baseline (592.344 us; speedup 1.0000x reference)
//
#include <hip/hip_runtime.h>

// NodeModel GNN: edge MLP (96->128->128->64 + LN) -> scatter_mean -> node MLP
// (128->128->128->64 + LN).  bf16 MFMA (16x16x32), fp32 accumulate.
//
// R2: dest-sorted edges (counting sort) + run-merged epilogue atomics,
//     persistent grid-stride blocks, cnt from histogram.
// R3: corruption-hardening (bounds-guard all global writes, clamp workspace-
//     derived indices, unsigned rdS packing, per-tile __syncthreads).
// R4: occupancy attack. Counters showed Occupancy 11% (1 block/CU: 142.8 KB
//     LDS), MfmaUtil 7.6%, HBM 9% -> latency-bound. Changes:
//     (1) weights read directly from global (L1/L2-resident 166 KB image) --
//         no LDS weight staging;
//     (2) atile+hid merged into ONE [128][136] buffer (rows are wave-private;
//         each layer fully reads its A-rows before overwriting them);
//     LDS 142.8 KB -> 37.1 KB  => 3 blocks/CU (VGPR-limited), 12 waves/CU.
//
// MFMA layouts (verified):
//   A-frag:  A[m = lane&15][k = (lane>>4)*8 + j]
//   B-frag:  B[k][n = lane&15] -> weights stored transposed [n][k]
//   C/D:     col n = lane&15, row m = (lane>>4)*4 + reg

#define NNODES 50000
#define NEDGES 800000
#define NTILES_E 6250    // 800000/128
#define NTILES_N 391     // ceil(50000/128)

typedef __bf16 bf16;
typedef __bf16 __attribute__((ext_vector_type(4))) bf16x4;
typedef __bf16 __attribute__((ext_vector_type(8))) bf16x8;
typedef float __attribute__((ext_vector_type(4))) f32x4;

__device__ __forceinline__ f32x4 mfma_bf16(bf16x8 a, bf16x8 b, f32x4 c) {
    return __builtin_amdgcn_mfma_f32_16x16x32_bf16(a, b, c, 0, 0, 0);
}

// ---- weight image layout (bf16, transposed [n][k], k-padded) ----
// k1: w0t 128x104 @0 (13312) | w1t 128x136 @13312 (17408) | w2t 64x136 @30720 (8704)
// k2: w0t 128x136 @39424     | w1t 128x136 @56832         | w2t 64x136 @74240
__global__ void prep_weights(const float* __restrict__ w10, const float* __restrict__ w11,
                             const float* __restrict__ w12, const float* __restrict__ w20,
                             const float* __restrict__ w21, const float* __restrict__ w22,
                             bf16* __restrict__ img) {
    int idx = blockIdx.x * 256 + threadIdx.x;
    float f;
    if (idx < 13312) {
        int n = idx / 104, k = idx % 104;
        f = (k < 96) ? w10[k * 128 + n] : 0.0f;
    } else if (idx < 30720) {
        int t = idx - 13312; int n = t / 136, k = t % 136;
        f = (k < 128) ? w11[k * 128 + n] : 0.0f;
    } else if (idx < 39424) {
        int t = idx - 30720; int n = t / 136, k = t % 136;
        f = (k < 128) ? w12[k * 64 + n] : 0.0f;
    } else if (idx < 56832) {
        int t = idx - 39424; int n = t / 136, k = t % 136;
        f = (k < 128) ? w20[k * 128 + n] : 0.0f;
    } else if (idx < 74240) {
        int t = idx - 56832; int n = t / 136, k = t % 136;
        f = (k < 128) ? w21[k * 128 + n] : 0.0f;
    } else if (idx < 82944) {
        int t = idx - 74240; int n = t / 136, k = t % 136;
        f = (k < 128) ? w22[k * 64 + n] : 0.0f;
    } else {
        return;
    }
    img[idx] = (bf16)f;
}

// ---- counting sort of edges by destination ----
__global__ void hist_kernel(const int* __restrict__ col, int* __restrict__ hist) {
    int i = blockIdx.x * 512 + threadIdx.x;
    if (i < NEDGES) {
        int d = col[i];
        if ((unsigned)d < (unsigned)NNODES) atomicAdd(hist + d, 1);
    }
}

__global__ void scanA(const int* __restrict__ hist, int* __restrict__ off,
                      int* __restrict__ csum) {
    __shared__ int sd[512];
    int t = threadIdx.x, i = blockIdx.x * 512 + t;
    int v = (i < NNODES) ? hist[i] : 0;
    sd[t] = v;
    __syncthreads();
    for (int o2 = 1; o2 < 512; o2 <<= 1) {
        int x = (t >= o2) ? sd[t - o2] : 0;
        __syncthreads();
        sd[t] += x;
        __syncthreads();
    }
    if (i < NNODES) off[i] = sd[t] - v;  // exclusive
    if (t == 511) csum[blockIdx.x] = sd[511];
}

__global__ void scanB(int* __restrict__ csum) {  // 1 block, 128 threads, 98 live
    __shared__ int sd[128];
    int t = threadIdx.x;
    int v = (t < 98) ? csum[t] : 0;
    sd[t] = v;
    __syncthreads();
    for (int o2 = 1; o2 < 128; o2 <<= 1) {
        int x = (t >= o2) ? sd[t - o2] : 0;
        __syncthreads();
        sd[t] += x;
        __syncthreads();
    }
    if (t < 98) csum[t] = sd[t] - v;  // exclusive chunk offsets
}

__global__ void scanC(int* __restrict__ off, const int* __restrict__ csum) {
    int i = blockIdx.x * 512 + threadIdx.x;
    if (i < NNODES) off[i] += csum[blockIdx.x];
}

// scatter: perm[pos]=edge id (sorted by dest); rdS[pos] = row | dest<<16 (unsigned)
__global__ void scatter_kernel(const int* __restrict__ eidx, int* __restrict__ off,
                               int* __restrict__ perm, int* __restrict__ rdS) {
    int i = blockIdx.x * 512 + threadIdx.x;
    if (i < NEDGES) {
        int r = eidx[i], d = eidx[NEDGES + i];
        if ((unsigned)d < (unsigned)NNODES && (unsigned)r < (unsigned)NNODES) {
            int pos = atomicAdd(off + d, 1);
            if ((unsigned)pos < (unsigned)NEDGES) {
                perm[pos] = i;
                rdS[pos] = (int)(((unsigned)r & 0xFFFFu) | ((unsigned)d << 16));
            }
        }
    }
}

__global__ __launch_bounds__(256) void edge_mlp(
    const float* __restrict__ x, const int* __restrict__ perm,
    const int* __restrict__ rdS, const float* __restrict__ eattr,
    const bf16* __restrict__ wimg,
    const float* __restrict__ b0g, const float* __restrict__ b1g,
    const float* __restrict__ b2g, const float* __restrict__ lng,
    const float* __restrict__ lnb, float* __restrict__ agg) {
    __shared__ __align__(16) bf16 buf[128 * 136];   // concat-input, then hid (in-place)
    __shared__ float bs[448];
    __shared__ int dstile[128];

    const int tid = threadIdx.x;
    if (tid < 128) { bs[tid] = b0g[tid]; bs[128 + tid] = b1g[tid]; }
    else {
        int t = tid - 128;
        if (t < 64) { bs[256 + t] = b2g[t]; bs[320 + t] = lng[t]; bs[384 + t] = lnb[t]; }
    }
    __syncthreads();

    const int lane = tid & 63;
    const int wv = tid >> 6;
    const int col16 = lane & 15;
    const int quad = lane >> 4;

    float b0r[8], b1r[8], b2r[4], gr[4], br[4];
#pragma unroll
    for (int i = 0; i < 8; i++) { b0r[i] = bs[i * 16 + col16]; b1r[i] = bs[128 + i * 16 + col16]; }
#pragma unroll
    for (int i = 0; i < 4; i++) {
        b2r[i] = bs[256 + i * 16 + col16];
        gr[i] = bs[320 + i * 16 + col16];
        br[i] = bs[384 + i * 16 + col16];
    }

    // weights straight from global (L1/L2-resident image)
    const bf16* w0t = wimg;
    const bf16* w1t = wimg + 13312;
    const bf16* w2t = wimg + 30720;

    const f32x4 vzero = {0.0f, 0.0f, 0.0f, 0.0f};
    const int r0 = wv * 32 + col16;     // A-frag row (mt=0)
    const int rw = wv * 32 + quad * 4;  // C/D row base (+ mt*16 + reg)
    const int el = tid >> 1, half = tid & 1;

    for (int tile = blockIdx.x; tile < NTILES_E; tile += gridDim.x) {
        const int sbase = tile * 128;
        // ---- stage A tile: concat(x[row], eattr) for sorted slot s ----
        {
            const int s = sbase + el;
            const unsigned v = (unsigned)rdS[s];
            int e = perm[s];
            int r = (int)(v & 0xFFFFu);
            unsigned d = v >> 16;
            if (r >= NNODES) r = 0;                        // clamp (corrupt-safe)
            if ((unsigned)e >= (unsigned)NEDGES) e = 0;    // clamp (corrupt-safe)
            if (half == 0) dstile[el] = (d < (unsigned)NNODES) ? (int)d : 0;
            const float4* xs = (const float4*)(x + (size_t)r * 64);
            bf16* arow = buf + el * 136;
#pragma unroll
            for (int j = 0; j < 8; j++) {
                float4 vv = xs[half * 8 + j];
                bf16x4 u = {(bf16)vv.x, (bf16)vv.y, (bf16)vv.z, (bf16)vv.w};
                *(bf16x4*)(arow + half * 32 + j * 4) = u;
            }
            const float4* es = (const float4*)(eattr + (size_t)e * 32);
#pragma unroll
            for (int j = 0; j < 4; j++) {
                float4 vv = es[half * 4 + j];
                bf16x4 u = {(bf16)vv.x, (bf16)vv.y, (bf16)vv.z, (bf16)vv.w};
                *(bf16x4*)(arow + 64 + half * 16 + j * 4) = u;
            }
        }
        __syncthreads();  // staging complete before compute

        // ---- layer 1: [32x96] @ [96x128] ----
        f32x4 acc1[2][8];
#pragma unroll
        for (int mt = 0; mt < 2; mt++)
#pragma unroll
            for (int nt = 0; nt < 8; nt++) acc1[mt][nt] = vzero;
#pragma unroll
        for (int ks = 0; ks < 3; ks++) {
            bf16x8 a0 = *(const bf16x8*)(buf + r0 * 136 + ks * 32 + quad * 8);
            bf16x8 a1 = *(const bf16x8*)(buf + (r0 + 16) * 136 + ks * 32 + quad * 8);
#pragma unroll
            for (int nt = 0; nt < 8; nt++) {
                bf16x8 b = *(const bf16x8*)(w0t + (nt * 16 + col16) * 104 + ks * 32 + quad * 8);
                acc1[0][nt] = mfma_bf16(a0, b, acc1[0][nt]);
                acc1[1][nt] = mfma_bf16(a1, b, acc1[1][nt]);
            }
        }
        // in-place: rows are wave-private; all reads above precede these writes
#pragma unroll
        for (int mt = 0; mt < 2; mt++)
#pragma unroll
            for (int nt = 0; nt < 8; nt++)
#pragma unroll
                for (int rg = 0; rg < 4; rg++) {
                    float v = acc1[mt][nt][rg] + b0r[nt];
                    v = (v > 0.0f) ? v : 0.01f * v;
                    buf[(rw + mt * 16 + rg) * 136 + nt * 16 + col16] = (bf16)v;
                }

        // ---- layer 2: [32x128] @ [128x128] ----
        bf16x8 a2[2][4];
#pragma unroll
        for (int mt = 0; mt < 2; mt++)
#pragma unroll
            for (int ks = 0; ks < 4; ks++)
                a2[mt][ks] = *(const bf16x8*)(buf + (r0 + mt * 16) * 136 + ks * 32 + quad * 8);
        f32x4 acc2[2][8];
#pragma unroll
        for (int mt = 0; mt < 2; mt++)
#pragma unroll
            for (int nt = 0; nt < 8; nt++) acc2[mt][nt] = vzero;
#pragma unroll
        for (int ks = 0; ks < 4; ks++) {
#pragma unroll
            for (int nt = 0; nt < 8; nt++) {
                bf16x8 b = *(const bf16x8*)(w1t + (nt * 16 + col16) * 136 + ks * 32 + quad * 8);
                acc2[0][nt] = mfma_bf16(a2[0][ks], b, acc2[0][nt]);
                acc2[1][nt] = mfma_bf16(a2[1][ks], b, acc2[1][nt]);
            }
        }
#pragma unroll
        for (int mt = 0; mt < 2; mt++)
#pragma unroll
            for (int nt = 0; nt < 8; nt++)
#pragma unroll
                for (int rg = 0; rg < 4; rg++) {
                    float v = acc2[mt][nt][rg] + b1r[nt];
                    v = (v > 0.0f) ? v : 0.01f * v;
                    buf[(rw + mt * 16 + rg) * 136 + nt * 16 + col16] = (bf16)v;
                }

        // ---- layer 3: [32x128] @ [128x64] ----
        bf16x8 a3[2][4];
#pragma unroll
        for (int mt = 0; mt < 2; mt++)
#pragma unroll
            for (int ks = 0; ks < 4; ks++)
                a3[mt][ks] = *(const bf16x8*)(buf + (r0 + mt * 16) * 136 + ks * 32 + quad * 8);
        f32x4 acc3[2][4];
#pragma unroll
        for (int mt = 0; mt < 2; mt++)
#pragma unroll
            for (int nt = 0; nt < 4; nt++) acc3[mt][nt] = vzero;
#pragma unroll
        for (int ks = 0; ks < 4; ks++) {
#pragma unroll
            for (int nt = 0; nt < 4; nt++) {
                bf16x8 b = *(const bf16x8*)(w2t + (nt * 16 + col16) * 136 + ks * 32 + quad * 8);
                acc3[0][nt] = mfma_bf16(a3[0][ks], b, acc3[0][nt]);
                acc3[1][nt] = mfma_bf16(a3[1][ks], b, acc3[1][nt]);
            }
        }

        // ---- epilogue: bias + lrelu + LN(64) + run-merged atomic scatter ----
#pragma unroll
        for (int mt = 0; mt < 2; mt++) {
            float vals[4][4];  // [nt][rg]
            float s1[4] = {0.f, 0.f, 0.f, 0.f}, s2[4] = {0.f, 0.f, 0.f, 0.f};
#pragma unroll
            for (int nt = 0; nt < 4; nt++)
#pragma unroll
                for (int rg = 0; rg < 4; rg++) {
                    float v = acc3[mt][nt][rg] + b2r[nt];
                    v = (v > 0.0f) ? v : 0.01f * v;
                    vals[nt][rg] = v;
                    s1[rg] += v;
                    s2[rg] += v * v;
                }
#pragma unroll
            for (int off2 = 1; off2 < 16; off2 <<= 1) {
#pragma unroll
                for (int rg = 0; rg < 4; rg++) {
                    s1[rg] += __shfl_xor(s1[rg], off2);
                    s2[rg] += __shfl_xor(s2[rg], off2);
                }
            }
            float o[4][4];
            int dr[4];
#pragma unroll
            for (int rg = 0; rg < 4; rg++) {
                float mu = s1[rg] * 0.015625f;
                float var = s2[rg] * 0.015625f - mu * mu;
                float rstd = rsqrtf(var + 1e-5f);
                int c = dstile[rw + mt * 16 + rg];
                dr[rg] = ((unsigned)c < (unsigned)NNODES) ? c : 0;  // corrupt-safe
#pragma unroll
                for (int nt = 0; nt < 4; nt++)
                    o[nt][rg] = (vals[nt][rg] - mu) * rstd * gr[nt] + br[nt];
            }
            // run-merge consecutive equal destinations (edges dest-sorted)
            float run0 = o[0][0], run1 = o[1][0], run2 = o[2][0], run3 = o[3][0];
            int cur = dr[0];
#pragma unroll
            for (int rg = 1; rg < 4; rg++) {
                if (dr[rg] != cur) {
                    float* dst = agg + (size_t)cur * 64 + col16;
                    atomicAdd(dst, run0); atomicAdd(dst + 16, run1);
                    atomicAdd(dst + 32, run2); atomicAdd(dst + 48, run3);
                    run0 = o[0][rg]; run1 = o[1][rg]; run2 = o[2][rg]; run3 = o[3][rg];
                    cur = dr[rg];
                } else {
                    run0 += o[0][rg]; run1 += o[1][rg]; run2 += o[2][rg]; run3 += o[3][rg];
                }
            }
            float* dst = agg + (size_t)cur * 64 + col16;
            atomicAdd(dst, run0); atomicAdd(dst + 16, run1);
            atomicAdd(dst + 32, run2); atomicAdd(dst + 48, run3);
        }
        __syncthreads();  // all reads of buf done before next staging
    }
}

__global__ __launch_bounds__(256) void node_mlp(
    const float* __restrict__ x, const float* __restrict__ agg,
    const int* __restrict__ hist, const bf16* __restrict__ wimg,
    const float* __restrict__ b0g, const float* __restrict__ b1g,
    const float* __restrict__ b2g, const float* __restrict__ lng,
    const float* __restrict__ lnb, float* __restrict__ out) {
    __shared__ __align__(16) bf16 buf[128 * 136];   // concat-input, then hid (in-place)
    __shared__ float bs[448];

    const int tid = threadIdx.x;
    if (tid < 128) { bs[tid] = b0g[tid]; bs[128 + tid] = b1g[tid]; }
    else {
        int t = tid - 128;
        if (t < 64) { bs[256 + t] = b2g[t]; bs[320 + t] = lng[t]; bs[384 + t] = lnb[t]; }
    }
    __syncthreads();

    const int lane = tid & 63;
    const int wv = tid >> 6;
    const int col16 = lane & 15;
    const int quad = lane >> 4;

    float b0r[8], b1r[8], b2r[4], gr[4], br[4];
#pragma unroll
    for (int i = 0; i < 8; i++) { b0r[i] = bs[i * 16 + col16]; b1r[i] = bs[128 + i * 16 + col16]; }
#pragma unroll
    for (int i = 0; i < 4; i++) {
        b2r[i] = bs[256 + i * 16 + col16];
        gr[i] = bs[320 + i * 16 + col16];
        br[i] = bs[384 + i * 16 + col16];
    }

    const bf16* w0t = wimg;
    const bf16* w1t = wimg + 17408;
    const bf16* w2t = wimg + 34816;

    const f32x4 vzero = {0.0f, 0.0f, 0.0f, 0.0f};
    const int r0 = wv * 32 + col16;
    const int rw = wv * 32 + quad * 4;
    const int el = tid >> 1, half = tid & 1;

    for (int tile = blockIdx.x; tile < NTILES_N; tile += gridDim.x) {
        const int nbase = tile * 128;
        // ---- stage A: concat(x[i], agg[i]/max(cnt,1)) ----
        {
            int i = nbase + el;
            if (i >= NNODES) i = NNODES - 1;  // clamp; tail rows never stored
            const float4* xs = (const float4*)(x + (size_t)i * 64);
            bf16* arow = buf + el * 136;
#pragma unroll
            for (int j = 0; j < 8; j++) {
                float4 v = xs[half * 8 + j];
                bf16x4 u = {(bf16)v.x, (bf16)v.y, (bf16)v.z, (bf16)v.w};
                *(bf16x4*)(arow + half * 32 + j * 4) = u;
            }
            int c = hist[i];
            float inv = 1.0f / (float)(c > 1 ? c : 1);
            const float4* as = (const float4*)(agg + (size_t)i * 64);
#pragma unroll
            for (int j = 0; j < 8; j++) {
                float4 v = as[half * 8 + j];
                bf16x4 u = {(bf16)(v.x * inv), (bf16)(v.y * inv), (bf16)(v.z * inv), (bf16)(v.w * inv)};
                *(bf16x4*)(arow + 64 + half * 32 + j * 4) = u;
            }
        }
        __syncthreads();

        // ---- layer 1 ----
        f32x4 acc1[2][8];
#pragma unroll
        for (int mt = 0; mt < 2; mt++)
#pragma unroll
            for (int nt = 0; nt < 8; nt++) acc1[mt][nt] = vzero;
#pragma unroll
        for (int ks = 0; ks < 4; ks++) {
            bf16x8 a0 = *(const bf16x8*)(buf + r0 * 136 + ks * 32 + quad * 8);
            bf16x8 a1 = *(const bf16x8*)(buf + (r0 + 16) * 136 + ks * 32 + quad * 8);
#pragma unroll
            for (int nt = 0; nt < 8; nt++) {
                bf16x8 b = *(const bf16x8*)(w0t + (nt * 16 + col16) * 136 + ks * 32 + quad * 8);
                acc1[0][nt] = mfma_bf16(a0, b, acc1[0][nt]);
                acc1[1][nt] = mfma_bf16(a1, b, acc1[1][nt]);
            }
        }
#pragma unroll
        for (int mt = 0; mt < 2; mt++)
#pragma unroll
            for (int nt = 0; nt < 8; nt++)
#pragma unroll
                for (int rg = 0; rg < 4; rg++) {
                    float v = acc1[mt][nt][rg] + b0r[nt];
                    v = (v > 0.0f) ? v : 0.01f * v;
                    buf[(rw + mt * 16 + rg) * 136 + nt * 16 + col16] = (bf16)v;
                }

        // ---- layer 2 ----
        bf16x8 a2[2][4];
#pragma unroll
        for (int mt = 0; mt < 2; mt++)
#pragma unroll
            for (int ks = 0; ks < 4; ks++)
                a2[mt][ks] = *(const bf16x8*)(buf + (r0 + mt * 16) * 136 + ks * 32 + quad * 8);
        f32x4 acc2[2][8];
#pragma unroll
        for (int mt = 0; mt < 2; mt++)
#pragma unroll
            for (int nt = 0; nt < 8; nt++) acc2[mt][nt] = vzero;
#pragma unroll
        for (int ks = 0; ks < 4; ks++) {
#pragma unroll
            for (int nt = 0; nt < 8; nt++) {
                bf16x8 b = *(const bf16x8*)(w1t + (nt * 16 + col16) * 136 + ks * 32 + quad * 8);
                acc2[0][nt] = mfma_bf16(a2[0][ks], b, acc2[0][nt]);
                acc2[1][nt] = mfma_bf16(a2[1][ks], b, acc2[1][nt]);
            }
        }
#pragma unroll
        for (int mt = 0; mt < 2; mt++)
#pragma unroll
            for (int nt = 0; nt < 8; nt++)
#pragma unroll
                for (int rg = 0; rg < 4; rg++) {
                    float v = acc2[mt][nt][rg] + b1r[nt];
                    v = (v > 0.0f) ? v : 0.01f * v;
                    buf[(rw + mt * 16 + rg) * 136 + nt * 16 + col16] = (bf16)v;
                }

        // ---- layer 3 ----
        bf16x8 a3[2][4];
#pragma unroll
        for (int mt = 0; mt < 2; mt++)
#pragma unroll
            for (int ks = 0; ks < 4; ks++)
                a3[mt][ks] = *(const bf16x8*)(buf + (r0 + mt * 16) * 136 + ks * 32 + quad * 8);
        f32x4 acc3[2][4];
#pragma unroll
        for (int mt = 0; mt < 2; mt++)
#pragma unroll
            for (int nt = 0; nt < 4; nt++) acc3[mt][nt] = vzero;
#pragma unroll
        for (int ks = 0; ks < 4; ks++) {
#pragma unroll
            for (int nt = 0; nt < 4; nt++) {
                bf16x8 b = *(const bf16x8*)(w2t + (nt * 16 + col16) * 136 + ks * 32 + quad * 8);
                acc3[0][nt] = mfma_bf16(a3[0][ks], b, acc3[0][nt]);
                acc3[1][nt] = mfma_bf16(a3[1][ks], b, acc3[1][nt]);
            }
        }

        // ---- epilogue ----
#pragma unroll
        for (int mt = 0; mt < 2; mt++) {
            float vals[4][4];
            float s1[4] = {0.f, 0.f, 0.f, 0.f}, s2[4] = {0.f, 0.f, 0.f, 0.f};
#pragma unroll
            for (int nt = 0; nt < 4; nt++)
#pragma unroll
                for (int rg = 0; rg < 4; rg++) {
                    float v = acc3[mt][nt][rg] + b2r[nt];
                    v = (v > 0.0f) ? v : 0.01f * v;
                    vals[nt][rg] = v;
                    s1[rg] += v;
                    s2[rg] += v * v;
                }
#pragma unroll
            for (int off2 = 1; off2 < 16; off2 <<= 1) {
#pragma unroll
                for (int rg = 0; rg < 4; rg++) {
                    s1[rg] += __shfl_xor(s1[rg], off2);
                    s2[rg] += __shfl_xor(s2[rg], off2);
                }
            }
#pragma unroll
            for (int rg = 0; rg < 4; rg++) {
                float mu = s1[rg] * 0.015625f;
                float var = s2[rg] * 0.015625f - mu * mu;
                float rstd = rsqrtf(var + 1e-5f);
                int i = nbase + rw + mt * 16 + rg;
                if (i < NNODES) {
#pragma unroll
                    for (int nt = 0; nt < 4; nt++) {
                        float o = (vals[nt][rg] - mu) * rstd * gr[nt] + br[nt];
                        out[(size_t)i * 64 + nt * 16 + col16] = o;
                    }
                }
            }
        }
        __syncthreads();
    }
}

extern "C" void kernel_launch(void* const* d_in, const int* in_sizes, int n_in,
                              void* d_out, int out_size, void* d_ws, size_t ws_size,
                              hipStream_t stream) {
    (void)in_sizes; (void)n_in; (void)out_size; (void)ws_size;
    const float* x     = (const float*)d_in[0];
    const int*   eidx  = (const int*)d_in[1];
    const float* eattr = (const float*)d_in[2];
    const float* m1w0 = (const float*)d_in[5];
    const float* m1b0 = (const float*)d_in[6];
    const float* m1w1 = (const float*)d_in[7];
    const float* m1b1 = (const float*)d_in[8];
    const float* m1w2 = (const float*)d_in[9];
    const float* m1b2 = (const float*)d_in[10];
    const float* ln1g = (const float*)d_in[11];
    const float* ln1b = (const float*)d_in[12];
    const float* m2w0 = (const float*)d_in[13];
    const float* m2b0 = (const float*)d_in[14];
    const float* m2w1 = (const float*)d_in[15];
    const float* m2b1 = (const float*)d_in[16];
    const float* m2w2 = (const float*)d_in[17];
    const float* m2b2 = (const float*)d_in[18];
    const float* ln2g = (const float*)d_in[19];
    const float* ln2b = (const float*)d_in[20];

    // ---- workspace layout ----
    char* ws = (char*)d_ws;
    float* agg  = (float*)ws;                          // 12,800,000 B
    int*   hist = (int*)(ws + 12800000);               //    200,000 B
    int*   off  = (int*)(ws + 13000000);               //    200,000 B
    int*   csum = (int*)(ws + 13200000);               //        512 B
    int*   perm = (int*)(ws + 13200512);               //  3,200,000 B
    int*   rdS  = (int*)(ws + 16400512);               //  3,200,000 B
    bf16*  wimg = (bf16*)(ws + 19600512);              //    165,888 B

    // zero agg + hist (contiguous)
    hipMemsetAsync(d_ws, 0, 13000000, stream);
    prep_weights<<<324, 256, 0, stream>>>(m1w0, m1w1, m1w2, m2w0, m2w1, m2w2, wimg);
    // counting sort by destination
    hist_kernel<<<1563, 512, 0, stream>>>(eidx + NEDGES, hist);
    scanA<<<98, 512, 0, stream>>>(hist, off, csum);
    scanB<<<1, 128, 0, stream>>>(csum);
    scanC<<<98, 512, 0, stream>>>(off, csum);
    scatter_kernel<<<1563, 512, 0, stream>>>(eidx, off, perm, rdS);
    // persistent MLP kernels (LDS 37 KB -> 3 blocks/CU)
    edge_mlp<<<1250, 256, 0, stream>>>(x, perm, rdS, eattr, wimg, m1b0, m1b1, m1b2,
                                       ln1g, ln1b, agg);
    node_mlp<<<391, 256, 0, stream>>>(x, agg, hist, wimg + 39424,
                                      m2b0, m2b1, m2b2, ln2g, ln2b, (float*)d_out);
}

// Round 4
// 489.580 us; speedup vs baseline: 1.2099x; 1.2099x over previous
//
#include <hip/hip_runtime.h>

// NodeModel GNN: edge MLP (96->128->128->64 + LN) -> scatter_mean -> node MLP
// (128->128->128->64 + LN).  bf16 MFMA (16x16x32), fp32 accumulate.
//
// R2: dest-sorted edges (counting sort) + run-merged epilogue atomics.
// R3: corruption-hardening (bounds-guards, clamps, unsigned packing, barriers).
// R4: LDS diet + global weights -> VGPR 240, occupancy unchanged, no win.
// R5: 8-wave blocks + pipelined gathers + BARRIER-FREE loop -> absmax 0.243 FAIL.
//     Lesson (twice confirmed, R2 + R5): barrier-free wave-private LDS staging
//     is NOT safe on gfx950. Barriers are mandatory.
// R6: R5 structure with 2 barriers/tile, placed so prefetches are never
//     drained while young:
//       commit -> B1 -> issue gathers(t+G) -> MFMA layers -> read dstile -> B2
//       -> register-only epilogue (atomics overlap loop-back).
//     512 thr (8 waves = 2/SIMD), 256-row tiles, weights in LDS.
//
// MFMA layouts (verified):
//   A-frag:  A[m = lane&15][k = (lane>>4)*8 + j]
//   B-frag:  B[k][n = lane&15] -> weights stored transposed [n][k]
//   C/D:     col n = lane&15, row m = (lane>>4)*4 + reg

#define NNODES 50000
#define NEDGES 800000
#define NTILES_E2 3125   // 800000/256
#define NTILES_N2 196    // ceil(50000/256)

typedef __bf16 bf16;
typedef __bf16 __attribute__((ext_vector_type(4))) bf16x4;
typedef __bf16 __attribute__((ext_vector_type(8))) bf16x8;
typedef float __attribute__((ext_vector_type(4))) f32x4;

__device__ __forceinline__ f32x4 mfma_bf16(bf16x8 a, bf16x8 b, f32x4 c) {
    return __builtin_amdgcn_mfma_f32_16x16x32_bf16(a, b, c, 0, 0, 0);
}

// ---- weight image layout (bf16, transposed [n][k], k-padded) ----
// k1: w0t 128x104 @0 (13312) | w1t 128x136 @13312 (17408) | w2t 64x136 @30720 (8704)
// k2: w0t 128x136 @39424     | w1t 128x136 @56832         | w2t 64x136 @74240
__global__ void prep_weights(const float* __restrict__ w10, const float* __restrict__ w11,
                             const float* __restrict__ w12, const float* __restrict__ w20,
                             const float* __restrict__ w21, const float* __restrict__ w22,
                             bf16* __restrict__ img) {
    int idx = blockIdx.x * 256 + threadIdx.x;
    float f;
    if (idx < 13312) {
        int n = idx / 104, k = idx % 104;
        f = (k < 96) ? w10[k * 128 + n] : 0.0f;
    } else if (idx < 30720) {
        int t = idx - 13312; int n = t / 136, k = t % 136;
        f = (k < 128) ? w11[k * 128 + n] : 0.0f;
    } else if (idx < 39424) {
        int t = idx - 30720; int n = t / 136, k = t % 136;
        f = (k < 128) ? w12[k * 64 + n] : 0.0f;
    } else if (idx < 56832) {
        int t = idx - 39424; int n = t / 136, k = t % 136;
        f = (k < 128) ? w20[k * 128 + n] : 0.0f;
    } else if (idx < 74240) {
        int t = idx - 56832; int n = t / 136, k = t % 136;
        f = (k < 128) ? w21[k * 128 + n] : 0.0f;
    } else if (idx < 82944) {
        int t = idx - 74240; int n = t / 136, k = t % 136;
        f = (k < 128) ? w22[k * 64 + n] : 0.0f;
    } else {
        return;
    }
    img[idx] = (bf16)f;
}

// ---- counting sort of edges by destination ----
__global__ void hist_kernel(const int* __restrict__ col, int* __restrict__ hist) {
    int i = blockIdx.x * 512 + threadIdx.x;
    if (i < NEDGES) {
        int d = col[i];
        if ((unsigned)d < (unsigned)NNODES) atomicAdd(hist + d, 1);
    }
}

__global__ void scanA(const int* __restrict__ hist, int* __restrict__ off,
                      int* __restrict__ csum) {
    __shared__ int sd[512];
    int t = threadIdx.x, i = blockIdx.x * 512 + t;
    int v = (i < NNODES) ? hist[i] : 0;
    sd[t] = v;
    __syncthreads();
    for (int o2 = 1; o2 < 512; o2 <<= 1) {
        int x = (t >= o2) ? sd[t - o2] : 0;
        __syncthreads();
        sd[t] += x;
        __syncthreads();
    }
    if (i < NNODES) off[i] = sd[t] - v;  // exclusive
    if (t == 511) csum[blockIdx.x] = sd[511];
}

__global__ void scanB(int* __restrict__ csum) {  // 1 block, 128 threads, 98 live
    __shared__ int sd[128];
    int t = threadIdx.x;
    int v = (t < 98) ? csum[t] : 0;
    sd[t] = v;
    __syncthreads();
    for (int o2 = 1; o2 < 128; o2 <<= 1) {
        int x = (t >= o2) ? sd[t - o2] : 0;
        __syncthreads();
        sd[t] += x;
        __syncthreads();
    }
    if (t < 98) csum[t] = sd[t] - v;  // exclusive chunk offsets
}

__global__ void scanC(int* __restrict__ off, const int* __restrict__ csum) {
    int i = blockIdx.x * 512 + threadIdx.x;
    if (i < NNODES) off[i] += csum[blockIdx.x];
}

// scatter: perm[pos]=edge id (sorted by dest); rdS[pos] = row | dest<<16 (unsigned)
__global__ void scatter_kernel(const int* __restrict__ eidx, int* __restrict__ off,
                               int* __restrict__ perm, int* __restrict__ rdS) {
    int i = blockIdx.x * 512 + threadIdx.x;
    if (i < NEDGES) {
        int r = eidx[i], d = eidx[NEDGES + i];
        if ((unsigned)d < (unsigned)NNODES && (unsigned)r < (unsigned)NNODES) {
            int pos = atomicAdd(off + d, 1);
            if ((unsigned)pos < (unsigned)NEDGES) {
                perm[pos] = i;
                rdS[pos] = (int)(((unsigned)r & 0xFFFFu) | ((unsigned)d << 16));
            }
        }
    }
}

__global__ __launch_bounds__(512, 2) void edge_mlp(
    const float* __restrict__ x, const int* __restrict__ perm,
    const int* __restrict__ rdS, const float* __restrict__ eattr,
    const bf16* __restrict__ wimg,
    const float* __restrict__ b0g, const float* __restrict__ b1g,
    const float* __restrict__ b2g, const float* __restrict__ lng,
    const float* __restrict__ lnb, float* __restrict__ agg) {
    __shared__ __align__(16) bf16 wall[39424];      // 78,848 B
    __shared__ __align__(16) bf16 buf[256 * 136];   // 69,632 B (input then hid, in-place)
    __shared__ float bs[448];
    __shared__ int dstile[256];

    const int tid = threadIdx.x;
    {   // stage weights once per block
        const uint4* src = (const uint4*)wimg;
        uint4* dst = (uint4*)wall;
        for (int i = tid; i < 4928; i += 512) dst[i] = src[i];
    }
    if (tid < 128) { bs[tid] = b0g[tid]; bs[128 + tid] = b1g[tid]; }
    else if (tid < 192) {
        int t = tid - 128;
        bs[256 + t] = b2g[t]; bs[320 + t] = lng[t]; bs[384 + t] = lnb[t];
    }
    __syncthreads();

    const int lane = tid & 63;
    const int wv = tid >> 6;           // 0..7
    const int col16 = lane & 15;
    const int quad = lane >> 4;

    float b0r[8], b1r[8], b2r[4], gr[4], br[4];
#pragma unroll
    for (int i = 0; i < 8; i++) { b0r[i] = bs[i * 16 + col16]; b1r[i] = bs[128 + i * 16 + col16]; }
#pragma unroll
    for (int i = 0; i < 4; i++) {
        b2r[i] = bs[256 + i * 16 + col16];
        gr[i] = bs[320 + i * 16 + col16];
        br[i] = bs[384 + i * 16 + col16];
    }

    const bf16* w0t = wall;
    const bf16* w1t = wall + 13312;
    const bf16* w2t = wall + 30720;

    const f32x4 vzero = {0.0f, 0.0f, 0.0f, 0.0f};
    const int r0 = wv * 32 + col16;     // A-frag row (mt=0); rows [32wv,32wv+32)
    const int rw = wv * 32 + quad * 4;  // C/D row base (+ mt*16 + reg)
    const int el = tid >> 1, half = tid & 1;   // thread stages half of row el
    const int G = gridDim.x;

    int tile = blockIdx.x;

    // ---- prologue: gathers(t0), indices(t1) ----
    float4 xr[8], er[4];
    unsigned cv;
    {
        int s = tile * 256 + el;
        cv = (unsigned)rdS[s];
        int ce = perm[s];
        int r = (int)(cv & 0xFFFFu); if (r >= NNODES) r = 0;
        if ((unsigned)ce >= (unsigned)NEDGES) ce = 0;
        const float4* xs = (const float4*)(x + (size_t)r * 64) + half * 8;
        const float4* es = (const float4*)(eattr + (size_t)ce * 32) + half * 4;
#pragma unroll
        for (int j = 0; j < 8; j++) xr[j] = xs[j];
#pragma unroll
        for (int j = 0; j < 4; j++) er[j] = es[j];
    }
    unsigned nv; int ne;
    {
        int t1 = tile + G;
        int s = (t1 < NTILES_E2 ? t1 * 256 : 0) + el;
        nv = (unsigned)rdS[s];
        ne = perm[s];
    }

    for (; tile < NTILES_E2; tile += G) {
        // ---- commit staged gathers (tile) to LDS ----
        {
            unsigned d = cv >> 16;
            if (half == 0) dstile[el] = (d < (unsigned)NNODES) ? (int)d : 0;
            bf16* arow = buf + el * 136;
#pragma unroll
            for (int j = 0; j < 8; j++) {
                float4 vv = xr[j];
                bf16x4 u = {(bf16)vv.x, (bf16)vv.y, (bf16)vv.z, (bf16)vv.w};
                *(bf16x4*)(arow + half * 32 + j * 4) = u;
            }
#pragma unroll
            for (int j = 0; j < 4; j++) {
                float4 vv = er[j];
                bf16x4 u = {(bf16)vv.x, (bf16)vv.y, (bf16)vv.z, (bf16)vv.w};
                *(bf16x4*)(arow + 64 + half * 16 + j * 4) = u;
            }
        }
        __syncthreads();   // B1: staging visible (only old atomics in vm queue)

        // ---- issue gathers(tile+G): fly during compute ----
        {
            int t2 = tile + G;
            if (t2 < NTILES_E2) {
                int r = (int)(nv & 0xFFFFu); if (r >= NNODES) r = 0;
                int e = ne; if ((unsigned)e >= (unsigned)NEDGES) e = 0;
                const float4* xs = (const float4*)(x + (size_t)r * 64) + half * 8;
                const float4* es = (const float4*)(eattr + (size_t)e * 32) + half * 4;
#pragma unroll
                for (int j = 0; j < 8; j++) xr[j] = xs[j];
#pragma unroll
                for (int j = 0; j < 4; j++) er[j] = es[j];
            }
        }
        // ---- prefetch indices(tile+2G) ----
        unsigned pv; int pe;
        {
            int t3 = tile + 2 * G;
            int s = (t3 < NTILES_E2 ? t3 * 256 : 0) + el;
            pv = (unsigned)rdS[s];
            pe = perm[s];
        }

        // ---- layer 1: [32x96] @ [96x128] ----
        f32x4 acc1[2][8];
#pragma unroll
        for (int mt = 0; mt < 2; mt++)
#pragma unroll
            for (int nt = 0; nt < 8; nt++) acc1[mt][nt] = vzero;
#pragma unroll
        for (int ks = 0; ks < 3; ks++) {
            bf16x8 a0 = *(const bf16x8*)(buf + r0 * 136 + ks * 32 + quad * 8);
            bf16x8 a1 = *(const bf16x8*)(buf + (r0 + 16) * 136 + ks * 32 + quad * 8);
#pragma unroll
            for (int nt = 0; nt < 8; nt++) {
                bf16x8 b = *(const bf16x8*)(w0t + (nt * 16 + col16) * 104 + ks * 32 + quad * 8);
                acc1[0][nt] = mfma_bf16(a0, b, acc1[0][nt]);
                acc1[1][nt] = mfma_bf16(a1, b, acc1[1][nt]);
            }
        }
        // in-place hid write: rows wave-private, reads precede writes in program order
#pragma unroll
        for (int mt = 0; mt < 2; mt++)
#pragma unroll
            for (int nt = 0; nt < 8; nt++)
#pragma unroll
                for (int rg = 0; rg < 4; rg++) {
                    float v = acc1[mt][nt][rg] + b0r[nt];
                    v = (v > 0.0f) ? v : 0.01f * v;
                    buf[(rw + mt * 16 + rg) * 136 + nt * 16 + col16] = (bf16)v;
                }

        // ---- layer 2: [32x128] @ [128x128] ----
        bf16x8 a2[2][4];
#pragma unroll
        for (int mt = 0; mt < 2; mt++)
#pragma unroll
            for (int ks = 0; ks < 4; ks++)
                a2[mt][ks] = *(const bf16x8*)(buf + (r0 + mt * 16) * 136 + ks * 32 + quad * 8);
        f32x4 acc2[2][8];
#pragma unroll
        for (int mt = 0; mt < 2; mt++)
#pragma unroll
            for (int nt = 0; nt < 8; nt++) acc2[mt][nt] = vzero;
#pragma unroll
        for (int ks = 0; ks < 4; ks++) {
#pragma unroll
            for (int nt = 0; nt < 8; nt++) {
                bf16x8 b = *(const bf16x8*)(w1t + (nt * 16 + col16) * 136 + ks * 32 + quad * 8);
                acc2[0][nt] = mfma_bf16(a2[0][ks], b, acc2[0][nt]);
                acc2[1][nt] = mfma_bf16(a2[1][ks], b, acc2[1][nt]);
            }
        }
#pragma unroll
        for (int mt = 0; mt < 2; mt++)
#pragma unroll
            for (int nt = 0; nt < 8; nt++)
#pragma unroll
                for (int rg = 0; rg < 4; rg++) {
                    float v = acc2[mt][nt][rg] + b1r[nt];
                    v = (v > 0.0f) ? v : 0.01f * v;
                    buf[(rw + mt * 16 + rg) * 136 + nt * 16 + col16] = (bf16)v;
                }

        // ---- layer 3: [32x128] @ [128x64] ----
        bf16x8 a3[2][4];
#pragma unroll
        for (int mt = 0; mt < 2; mt++)
#pragma unroll
            for (int ks = 0; ks < 4; ks++)
                a3[mt][ks] = *(const bf16x8*)(buf + (r0 + mt * 16) * 136 + ks * 32 + quad * 8);
        f32x4 acc3[2][4];
#pragma unroll
        for (int mt = 0; mt < 2; mt++)
#pragma unroll
            for (int nt = 0; nt < 4; nt++) acc3[mt][nt] = vzero;
#pragma unroll
        for (int ks = 0; ks < 4; ks++) {
#pragma unroll
            for (int nt = 0; nt < 4; nt++) {
                bf16x8 b = *(const bf16x8*)(w2t + (nt * 16 + col16) * 136 + ks * 32 + quad * 8);
                acc3[0][nt] = mfma_bf16(a3[0][ks], b, acc3[0][nt]);
                acc3[1][nt] = mfma_bf16(a3[1][ks], b, acc3[1][nt]);
            }
        }

        // ---- hoist dstile reads to registers (last LDS reads of this tile) ----
        int drA[2][4];
#pragma unroll
        for (int mt = 0; mt < 2; mt++)
#pragma unroll
            for (int rg = 0; rg < 4; rg++) {
                int c = dstile[rw + mt * 16 + rg];
                drA[mt][rg] = ((unsigned)c < (unsigned)NNODES) ? c : 0;  // corrupt-safe
            }
        __syncthreads();   // B2: all LDS reads done; prefetches are old -> free drain

        // ---- epilogue (register-only): bias + lrelu + LN(64) + merged atomics ----
#pragma unroll
        for (int mt = 0; mt < 2; mt++) {
            float vals[4][4];  // [nt][rg]
            float s1[4] = {0.f, 0.f, 0.f, 0.f}, s2[4] = {0.f, 0.f, 0.f, 0.f};
#pragma unroll
            for (int nt = 0; nt < 4; nt++)
#pragma unroll
                for (int rg = 0; rg < 4; rg++) {
                    float v = acc3[mt][nt][rg] + b2r[nt];
                    v = (v > 0.0f) ? v : 0.01f * v;
                    vals[nt][rg] = v;
                    s1[rg] += v;
                    s2[rg] += v * v;
                }
#pragma unroll
            for (int off2 = 1; off2 < 16; off2 <<= 1) {
#pragma unroll
                for (int rg = 0; rg < 4; rg++) {
                    s1[rg] += __shfl_xor(s1[rg], off2);
                    s2[rg] += __shfl_xor(s2[rg], off2);
                }
            }
            float o[4][4];
#pragma unroll
            for (int rg = 0; rg < 4; rg++) {
                float mu = s1[rg] * 0.015625f;
                float var = s2[rg] * 0.015625f - mu * mu;
                float rstd = rsqrtf(var + 1e-5f);
#pragma unroll
                for (int nt = 0; nt < 4; nt++)
                    o[nt][rg] = (vals[nt][rg] - mu) * rstd * gr[nt] + br[nt];
            }
            // run-merge consecutive equal destinations (edges dest-sorted)
            float run0 = o[0][0], run1 = o[1][0], run2 = o[2][0], run3 = o[3][0];
            int cur = drA[mt][0];
#pragma unroll
            for (int rg = 1; rg < 4; rg++) {
                if (drA[mt][rg] != cur) {
                    float* dst = agg + (size_t)cur * 64 + col16;
                    atomicAdd(dst, run0); atomicAdd(dst + 16, run1);
                    atomicAdd(dst + 32, run2); atomicAdd(dst + 48, run3);
                    run0 = o[0][rg]; run1 = o[1][rg]; run2 = o[2][rg]; run3 = o[3][rg];
                    cur = drA[mt][rg];
                } else {
                    run0 += o[0][rg]; run1 += o[1][rg]; run2 += o[2][rg]; run3 += o[3][rg];
                }
            }
            float* dst = agg + (size_t)cur * 64 + col16;
            atomicAdd(dst, run0); atomicAdd(dst + 16, run1);
            atomicAdd(dst + 32, run2); atomicAdd(dst + 48, run3);
        }

        // rotate pipeline state
        cv = nv; nv = pv; ne = pe;
    }
}

__global__ __launch_bounds__(512, 2) void node_mlp(
    const float* __restrict__ x, const float* __restrict__ agg,
    const int* __restrict__ hist, const bf16* __restrict__ wimg,
    const float* __restrict__ b0g, const float* __restrict__ b1g,
    const float* __restrict__ b2g, const float* __restrict__ lng,
    const float* __restrict__ lnb, float* __restrict__ out) {
    __shared__ __align__(16) bf16 wall[43520];      // 87,040 B
    __shared__ __align__(16) bf16 buf[256 * 136];   // 69,632 B
    __shared__ float bs[448];

    const int tid = threadIdx.x;
    {
        const uint4* src = (const uint4*)wimg;
        uint4* dst = (uint4*)wall;
        for (int i = tid; i < 5440; i += 512) dst[i] = src[i];
    }
    if (tid < 128) { bs[tid] = b0g[tid]; bs[128 + tid] = b1g[tid]; }
    else if (tid < 192) {
        int t = tid - 128;
        bs[256 + t] = b2g[t]; bs[320 + t] = lng[t]; bs[384 + t] = lnb[t];
    }
    __syncthreads();

    const int lane = tid & 63;
    const int wv = tid >> 6;
    const int col16 = lane & 15;
    const int quad = lane >> 4;

    float b0r[8], b1r[8], b2r[4], gr[4], br[4];
#pragma unroll
    for (int i = 0; i < 8; i++) { b0r[i] = bs[i * 16 + col16]; b1r[i] = bs[128 + i * 16 + col16]; }
#pragma unroll
    for (int i = 0; i < 4; i++) {
        b2r[i] = bs[256 + i * 16 + col16];
        gr[i] = bs[320 + i * 16 + col16];
        br[i] = bs[384 + i * 16 + col16];
    }

    const bf16* w0t = wall;
    const bf16* w1t = wall + 17408;
    const bf16* w2t = wall + 34816;

    const f32x4 vzero = {0.0f, 0.0f, 0.0f, 0.0f};
    const int r0 = wv * 32 + col16;
    const int rw = wv * 32 + quad * 4;
    const int el = tid >> 1, half = tid & 1;
    const int G = gridDim.x;

    int tile = blockIdx.x;
    if (tile >= NTILES_N2) return;

    // prologue: issue loads(t0)
    float4 xr[8], ar[8];
    int cc;
    {
        int i = tile * 256 + el;
        if (i >= NNODES) i = NNODES - 1;  // clamp; tail rows never stored
        const float4* xs = (const float4*)(x + (size_t)i * 64) + half * 8;
        const float4* as = (const float4*)(agg + (size_t)i * 64) + half * 8;
#pragma unroll
        for (int j = 0; j < 8; j++) { xr[j] = xs[j]; ar[j] = as[j]; }
        cc = hist[i];
    }

    for (; tile < NTILES_N2; tile += G) {
        const int nbase = tile * 256;
        // commit staged loads to LDS
        {
            float inv = 1.0f / (float)(cc > 1 ? cc : 1);
            bf16* arow = buf + el * 136;
#pragma unroll
            for (int j = 0; j < 8; j++) {
                float4 v = xr[j];
                bf16x4 u = {(bf16)v.x, (bf16)v.y, (bf16)v.z, (bf16)v.w};
                *(bf16x4*)(arow + half * 32 + j * 4) = u;
            }
#pragma unroll
            for (int j = 0; j < 8; j++) {
                float4 v = ar[j];
                bf16x4 u = {(bf16)(v.x * inv), (bf16)(v.y * inv), (bf16)(v.z * inv), (bf16)(v.w * inv)};
                *(bf16x4*)(arow + 64 + half * 32 + j * 4) = u;
            }
        }
        __syncthreads();   // B1

        // issue loads(t+G)
        {
            int t2 = tile + G;
            if (t2 < NTILES_N2) {
                int i = t2 * 256 + el;
                if (i >= NNODES) i = NNODES - 1;
                const float4* xs = (const float4*)(x + (size_t)i * 64) + half * 8;
                const float4* as = (const float4*)(agg + (size_t)i * 64) + half * 8;
#pragma unroll
                for (int j = 0; j < 8; j++) { xr[j] = xs[j]; ar[j] = as[j]; }
                cc = hist[i];
            }
        }

        // ---- layer 1 ----
        f32x4 acc1[2][8];
#pragma unroll
        for (int mt = 0; mt < 2; mt++)
#pragma unroll
            for (int nt = 0; nt < 8; nt++) acc1[mt][nt] = vzero;
#pragma unroll
        for (int ks = 0; ks < 4; ks++) {
            bf16x8 a0 = *(const bf16x8*)(buf + r0 * 136 + ks * 32 + quad * 8);
            bf16x8 a1 = *(const bf16x8*)(buf + (r0 + 16) * 136 + ks * 32 + quad * 8);
#pragma unroll
            for (int nt = 0; nt < 8; nt++) {
                bf16x8 b = *(const bf16x8*)(w0t + (nt * 16 + col16) * 136 + ks * 32 + quad * 8);
                acc1[0][nt] = mfma_bf16(a0, b, acc1[0][nt]);
                acc1[1][nt] = mfma_bf16(a1, b, acc1[1][nt]);
            }
        }
#pragma unroll
        for (int mt = 0; mt < 2; mt++)
#pragma unroll
            for (int nt = 0; nt < 8; nt++)
#pragma unroll
                for (int rg = 0; rg < 4; rg++) {
                    float v = acc1[mt][nt][rg] + b0r[nt];
                    v = (v > 0.0f) ? v : 0.01f * v;
                    buf[(rw + mt * 16 + rg) * 136 + nt * 16 + col16] = (bf16)v;
                }

        // ---- layer 2 ----
        bf16x8 a2[2][4];
#pragma unroll
        for (int mt = 0; mt < 2; mt++)
#pragma unroll
            for (int ks = 0; ks < 4; ks++)
                a2[mt][ks] = *(const bf16x8*)(buf + (r0 + mt * 16) * 136 + ks * 32 + quad * 8);
        f32x4 acc2[2][8];
#pragma unroll
        for (int mt = 0; mt < 2; mt++)
#pragma unroll
            for (int nt = 0; nt < 8; nt++) acc2[mt][nt] = vzero;
#pragma unroll
        for (int ks = 0; ks < 4; ks++) {
#pragma unroll
            for (int nt = 0; nt < 8; nt++) {
                bf16x8 b = *(const bf16x8*)(w1t + (nt * 16 + col16) * 136 + ks * 32 + quad * 8);
                acc2[0][nt] = mfma_bf16(a2[0][ks], b, acc2[0][nt]);
                acc2[1][nt] = mfma_bf16(a2[1][ks], b, acc2[1][nt]);
            }
        }
#pragma unroll
        for (int mt = 0; mt < 2; mt++)
#pragma unroll
            for (int nt = 0; nt < 8; nt++)
#pragma unroll
                for (int rg = 0; rg < 4; rg++) {
                    float v = acc2[mt][nt][rg] + b1r[nt];
                    v = (v > 0.0f) ? v : 0.01f * v;
                    buf[(rw + mt * 16 + rg) * 136 + nt * 16 + col16] = (bf16)v;
                }

        // ---- layer 3 ----
        bf16x8 a3[2][4];
#pragma unroll
        for (int mt = 0; mt < 2; mt++)
#pragma unroll
            for (int ks = 0; ks < 4; ks++)
                a3[mt][ks] = *(const bf16x8*)(buf + (r0 + mt * 16) * 136 + ks * 32 + quad * 8);
        f32x4 acc3[2][4];
#pragma unroll
        for (int mt = 0; mt < 2; mt++)
#pragma unroll
            for (int nt = 0; nt < 4; nt++) acc3[mt][nt] = vzero;
#pragma unroll
        for (int ks = 0; ks < 4; ks++) {
#pragma unroll
            for (int nt = 0; nt < 4; nt++) {
                bf16x8 b = *(const bf16x8*)(w2t + (nt * 16 + col16) * 136 + ks * 32 + quad * 8);
                acc3[0][nt] = mfma_bf16(a3[0][ks], b, acc3[0][nt]);
                acc3[1][nt] = mfma_bf16(a3[1][ks], b, acc3[1][nt]);
            }
        }
        __syncthreads();   // B2: all buf reads done before next commit

        // ---- epilogue (register-only) ----
#pragma unroll
        for (int mt = 0; mt < 2; mt++) {
            float vals[4][4];
            float s1[4] = {0.f, 0.f, 0.f, 0.f}, s2[4] = {0.f, 0.f, 0.f, 0.f};
#pragma unroll
            for (int nt = 0; nt < 4; nt++)
#pragma unroll
                for (int rg = 0; rg < 4; rg++) {
                    float v = acc3[mt][nt][rg] + b2r[nt];
                    v = (v > 0.0f) ? v : 0.01f * v;
                    vals[nt][rg] = v;
                    s1[rg] += v;
                    s2[rg] += v * v;
                }
#pragma unroll
            for (int off2 = 1; off2 < 16; off2 <<= 1) {
#pragma unroll
                for (int rg = 0; rg < 4; rg++) {
                    s1[rg] += __shfl_xor(s1[rg], off2);
                    s2[rg] += __shfl_xor(s2[rg], off2);
                }
            }
#pragma unroll
            for (int rg = 0; rg < 4; rg++) {
                float mu = s1[rg] * 0.015625f;
                float var = s2[rg] * 0.015625f - mu * mu;
                float rstd = rsqrtf(var + 1e-5f);
                int i = nbase + rw + mt * 16 + rg;
                if (i < NNODES) {
#pragma unroll
                    for (int nt = 0; nt < 4; nt++) {
                        float o = (vals[nt][rg] - mu) * rstd * gr[nt] + br[nt];
                        out[(size_t)i * 64 + nt * 16 + col16] = o;
                    }
                }
            }
        }
    }
}

extern "C" void kernel_launch(void* const* d_in, const int* in_sizes, int n_in,
                              void* d_out, int out_size, void* d_ws, size_t ws_size,
                              hipStream_t stream) {
    (void)in_sizes; (void)n_in; (void)out_size; (void)ws_size;
    const float* x     = (const float*)d_in[0];
    const int*   eidx  = (const int*)d_in[1];
    const float* eattr = (const float*)d_in[2];
    const float* m1w0 = (const float*)d_in[5];
    const float* m1b0 = (const float*)d_in[6];
    const float* m1w1 = (const float*)d_in[7];
    const float* m1b1 = (const float*)d_in[8];
    const float* m1w2 = (const float*)d_in[9];
    const float* m1b2 = (const float*)d_in[10];
    const float* ln1g = (const float*)d_in[11];
    const float* ln1b = (const float*)d_in[12];
    const float* m2w0 = (const float*)d_in[13];
    const float* m2b0 = (const float*)d_in[14];
    const float* m2w1 = (const float*)d_in[15];
    const float* m2b1 = (const float*)d_in[16];
    const float* m2w2 = (const float*)d_in[17];
    const float* m2b2 = (const float*)d_in[18];
    const float* ln2g = (const float*)d_in[19];
    const float* ln2b = (const float*)d_in[20];

    // ---- workspace layout ----
    char* ws = (char*)d_ws;
    float* agg  = (float*)ws;                          // 12,800,000 B
    int*   hist = (int*)(ws + 12800000);               //    200,000 B
    int*   off  = (int*)(ws + 13000000);               //    200,000 B
    int*   csum = (int*)(ws + 13200000);               //        512 B
    int*   perm = (int*)(ws + 13200512);               //  3,200,000 B
    int*   rdS  = (int*)(ws + 16400512);               //  3,200,000 B
    bf16*  wimg = (bf16*)(ws + 19600512);              //    165,888 B

    // zero agg + hist (contiguous)
    hipMemsetAsync(d_ws, 0, 13000000, stream);
    prep_weights<<<324, 256, 0, stream>>>(m1w0, m1w1, m1w2, m2w0, m2w1, m2w2, wimg);
    // counting sort by destination
    hist_kernel<<<1563, 512, 0, stream>>>(eidx + NEDGES, hist);
    scanA<<<98, 512, 0, stream>>>(hist, off, csum);
    scanB<<<1, 128, 0, stream>>>(csum);
    scanC<<<98, 512, 0, stream>>>(off, csum);
    scatter_kernel<<<1563, 512, 0, stream>>>(eidx, off, perm, rdS);
    // persistent MLP kernels: 512 threads (8 waves), 256-row tiles, 2 barriers/tile
    edge_mlp<<<256, 512, 0, stream>>>(x, perm, rdS, eattr, wimg, m1b0, m1b1, m1b2,
                                      ln1g, ln1b, agg);
    node_mlp<<<196, 512, 0, stream>>>(x, agg, hist, wimg + 39424,
                                      m2b0, m2b1, m2b2, ln2g, ln2b, (float*)d_out);
}